// Round 8
// baseline (103.190 us; speedup 1.0000x reference)
//
#include <hip/hip_runtime.h>

#define EMBED 256
#define NUM_DEPTH 128
#define CT_STRIDE 72   // 64 + 8 pad: rows = 144 B (16B-aligned), breaks pow-2 bank stride

typedef __attribute__((ext_vector_type(8))) short bf16x8;
typedef __attribute__((ext_vector_type(4))) float f32x4;

__device__ __forceinline__ unsigned short f2b(float f) {
    union { float f; unsigned u; } c; c.f = f;
    unsigned u = c.u;
    u += 0x7fffu + ((u >> 16) & 1u);   // RNE to bf16
    return (unsigned short)(u >> 16);
}
__device__ __forceinline__ float b2f(unsigned short h) {
    union { unsigned u; float f; } c; c.u = ((unsigned)h) << 16;
    return c.f;
}

// ---------------- Phase 1: fp32 -> bf16 conversion of key & value ----------------
__global__ __launch_bounds__(256) void cvt_kernel(
    const float4* __restrict__ key, const float4* __restrict__ val,
    ushort4* __restrict__ kb, ushort4* __restrict__ vb, int n4)
{
    int i = blockIdx.x * blockDim.x + threadIdx.x;
    if (i >= n4) return;
    float4 a = key[i];
    float4 b = val[i];
    kb[i] = make_ushort4(f2b(a.x), f2b(a.y), f2b(a.z), f2b(a.w));
    vb[i] = make_ushort4(f2b(b.x), f2b(b.y), f2b(b.z), f2b(b.w));
}

// ---------------- Phase 2: D[q][p] = sum_e key[q,e]*value[p,e]  (NT GEMM) --------
// 64x64 tile, 128 threads (2 waves), 16x16x32 bf16 MFMA, BK=32.
// 4096 blocks -> ~12 resident blocks/CU (vs 4 with 128-tiles): 3x more independent
// barrier-groups to hide the staging-latency rounds that dominate at K=256.
// Staging/fragment/epilogue index math identical to the validated R4 kernel.
__global__ __launch_bounds__(128) void gemm_nt_bf16(
    const unsigned short* __restrict__ A,   // key bf16 [M][256]
    const unsigned short* __restrict__ B,   // value bf16 [N][256]
    unsigned short* __restrict__ D,         // [M][N] bf16
    int N)
{
    __shared__ __align__(16) unsigned short Ct[64 * CT_STRIDE];  // 9216 B
    unsigned short* As = Ct;              // 64x32 = 4096 B (dead after K-loop)
    unsigned short* Bs = Ct + 2048;       // 4096 B (total 8192 <= 9216)

    const int m0 = blockIdx.y * 64;
    const int n0 = blockIdx.x * 64;
    const int tid  = threadIdx.x;
    const int lane = tid & 63;
    const int wave = tid >> 6;           // 0..1
    const int wm = wave * 32;            // m-half owned by this wave

    f32x4 acc[2][4] = {};

    const int srow = lane >> 2;          // row within 16-row chunk (staging)
    const int scol = (lane & 3) * 8;     // 8-elem col group
    const int k8 = (lane >> 4) * 8;      // fragment k-slice
    const int fm = lane & 15;            // fragment row within 16

    for (int kt = 0; kt < EMBED; kt += 32) {
        #pragma unroll
        for (int t = 0; t < 2; ++t) {
            const int c = wave * 2 + t;          // 16-row chunk 0..3
            const int row = c * 16 + srow;
            const unsigned short* ga = A + (size_t)(m0 + row) * EMBED + kt + scol;
            const unsigned short* gb = B + (size_t)(n0 + row) * EMBED + kt + scol;
            __builtin_amdgcn_global_load_lds(
                (const __attribute__((address_space(1))) void*)ga,
                (__attribute__((address_space(3))) void*)(As + c * 512), 16, 0, 0);
            __builtin_amdgcn_global_load_lds(
                (const __attribute__((address_space(1))) void*)gb,
                (__attribute__((address_space(3))) void*)(Bs + c * 512), 16, 0, 0);
        }
        __syncthreads();

        bf16x8 af[2], bfr[4];
        #pragma unroll
        for (int i = 0; i < 2; ++i)
            af[i]  = *(const bf16x8*)(As + (wm + i * 16 + fm) * 32 + k8);
        #pragma unroll
        for (int j = 0; j < 4; ++j)
            bfr[j] = *(const bf16x8*)(Bs + (j * 16 + fm) * 32 + k8);
        #pragma unroll
        for (int i = 0; i < 2; ++i)
            #pragma unroll
            for (int j = 0; j < 4; ++j)
                acc[i][j] = __builtin_amdgcn_mfma_f32_16x16x32_bf16(af[i], bfr[j], acc[i][j], 0, 0, 0);
        __syncthreads();   // As/Bs dead after final iter -> Ct reuse below is safe
    }

    // ---- Epilogue: fragments -> Ct (bf16), then coalesced dwordx4 stores ----
    // C/D layout: col=lane&15, row=(lane>>4)*4+r
    const int col = lane & 15;
    const int rbase = (lane >> 4) * 4;
    #pragma unroll
    for (int i = 0; i < 2; ++i)
        #pragma unroll
        for (int j = 0; j < 4; ++j) {
            const int rr = wm + i * 16 + rbase;
            const int cc = j * 16 + col;
            #pragma unroll
            for (int r = 0; r < 4; ++r)
                Ct[(rr + r) * CT_STRIDE + cc] = f2b(acc[i][j][r]);
        }
    __syncthreads();

    #pragma unroll
    for (int it = 0; it < 4; ++it) {
        const int r  = it * 16 + (tid >> 3);   // 0..63
        const int c8 = (tid & 7) * 8;          // 8-ushort chunk, covers 64 cols
        const int4 v = *(const int4*)(Ct + r * CT_STRIDE + c8);
        *(int4*)(D + (size_t)(m0 + r) * N + n0 + c8) = v;
    }
}

// ---------------- Phase 3: bilinear gather (LDS-staged D rows) + identity -------
__global__ __launch_bounds__(256) void gather_kernel(
    const unsigned short* __restrict__ D,   // [nq][nv] bf16
    const float* __restrict__ identity,     // [nq*128]
    const float* __restrict__ ref3d,        // [nq*128][2]
    const int*   __restrict__ spatial,      // {H, W}
    float* __restrict__ out, int nv)
{
    __shared__ unsigned short Ds[2 * 4096];  // 16 KB (nv <= 4096 guarded on host)

    const int q0 = blockIdx.x * 2;
    const int tid = threadIdx.x;

    const int4* src = (const int4*)(D + (size_t)q0 * nv);
    int4* dst = (int4*)Ds;
    const int nchunk = (2 * nv) / 8;
    for (int i = tid; i < nchunk; i += 256) dst[i] = src[i];
    __syncthreads();

    const int Hs = spatial[0], Ws = spatial[1];
    const int l = q0 * NUM_DEPTH + tid;      // 256 threads == 2 q * 128 d
    const int qi = tid >> 7;

    const float2 r2 = reinterpret_cast<const float2*>(ref3d)[l];
    const float px = r2.x * (float)Ws - 0.5f;
    const float py = r2.y * (float)Hs - 0.5f;
    const float x0f = floorf(px), y0f = floorf(py);
    const int ix0 = (int)x0f, iy0 = (int)y0f;
    const int ix1 = ix0 + 1,  iy1 = iy0 + 1;
    const float wx1 = px - x0f, wx0 = 1.0f - wx1;
    const float wy1 = py - y0f, wy0 = 1.0f - wy1;
    const bool vx0 = (ix0 >= 0) & (ix0 < Ws);
    const bool vx1 = (ix1 >= 0) & (ix1 < Ws);

    const unsigned short* row = Ds + qi * nv;
    float acc = 0.f;
    if (iy0 >= 0 && iy0 < Hs) {
        if (vx0) acc = fmaf(wy0 * wx0, b2f(row[iy0 * Ws + ix0]), acc);
        if (vx1) acc = fmaf(wy0 * wx1, b2f(row[iy0 * Ws + ix1]), acc);
    }
    if (iy1 >= 0 && iy1 < Hs) {
        if (vx0) acc = fmaf(wy1 * wx0, b2f(row[iy1 * Ws + ix0]), acc);
        if (vx1) acc = fmaf(wy1 * wx1, b2f(row[iy1 * Ws + ix1]), acc);
    }
    out[l] = fmaf(acc, 0.0625f, identity[l]);  // 1/sqrt(256) = 1/16
}

// ---------------- Fallback (round-1 direct kernel) ----------------
__global__ __launch_bounds__(256) void uv_direct_kernel(
    const float* __restrict__ key, const float* __restrict__ value,
    const float* __restrict__ identity, const float* __restrict__ ref3d,
    const int* __restrict__ spatial, float* __restrict__ out)
{
    const int q = blockIdx.x;
    const int tid = threadIdx.x;
    const int lane = tid & 63;
    const int wave = tid >> 6;
    const int H = spatial[0], W = spatial[1];
    const int row4 = EMBED / 4;
    const float4 k4 = reinterpret_cast<const float4*>(key + (size_t)q * EMBED)[lane];
    const float4* __restrict__ v4 = reinterpret_cast<const float4*>(value);
    for (int d = wave; d < NUM_DEPTH; d += 4) {
        const int l = q * NUM_DEPTH + d;
        const float rx = ref3d[2 * l], ry = ref3d[2 * l + 1];
        const float px = rx * (float)W - 0.5f, py = ry * (float)H - 0.5f;
        const float x0f = floorf(px), y0f = floorf(py);
        const int ix0 = (int)x0f, iy0 = (int)y0f, ix1 = ix0 + 1, iy1 = iy0 + 1;
        const float wx1 = px - x0f, wx0 = 1.f - wx1, wy1 = py - y0f, wy0 = 1.f - wy1;
        float4 acc = make_float4(0.f, 0.f, 0.f, 0.f);
        #define TAP(IY, IX, WGT) \
            if ((IY) >= 0 && (IY) < H && (IX) >= 0 && (IX) < W) { \
                const float w_ = (WGT); \
                const float4 t = v4[(size_t)((IY) * W + (IX)) * row4 + lane]; \
                acc.x = fmaf(w_, t.x, acc.x); acc.y = fmaf(w_, t.y, acc.y); \
                acc.z = fmaf(w_, t.z, acc.z); acc.w = fmaf(w_, t.w, acc.w); }
        TAP(iy0, ix0, wy0 * wx0) TAP(iy0, ix1, wy0 * wx1)
        TAP(iy1, ix0, wy1 * wx0) TAP(iy1, ix1, wy1 * wx1)
        #undef TAP
        float partial = acc.x * k4.x + acc.y * k4.y + acc.z * k4.z + acc.w * k4.w;
        #pragma unroll
        for (int off = 32; off > 0; off >>= 1) partial += __shfl_xor(partial, off, 64);
        if (lane == 0) out[l] = fmaf(partial, 0.0625f, identity[l]);
    }
}

extern "C" void kernel_launch(void* const* d_in, const int* in_sizes, int n_in,
                              void* d_out, int out_size, void* d_ws, size_t ws_size,
                              hipStream_t stream) {
    // inputs: 0 query(unused) 1 key 2 value 3 identity 4 ref_3d 5 spatial 6 W_attn(unused) 7 b_attn(unused)
    const float* key      = (const float*)d_in[1];
    const float* value    = (const float*)d_in[2];
    const float* identity = (const float*)d_in[3];
    const float* ref3d    = (const float*)d_in[4];
    const int*   spatial  = (const int*)d_in[5];
    float* out = (float*)d_out;

    const int nq = in_sizes[3] / NUM_DEPTH;   // 4096 queries
    const int nv = in_sizes[1] / EMBED;       // 4096 pixels (= H*W)

    const size_t d_bytes  = (size_t)nq * nv * sizeof(unsigned short);
    const size_t kb_bytes = (size_t)nq * EMBED * sizeof(unsigned short);
    const size_t vb_bytes = (size_t)nv * EMBED * sizeof(unsigned short);
    const size_t need = d_bytes + kb_bytes + vb_bytes;

    if (ws_size < need || (nq % 64) || (nv % 64) || nv > 4096 || (nq % 2)) {
        uv_direct_kernel<<<nq, 256, 0, stream>>>(key, value, identity, ref3d, spatial, out);
        return;
    }

    unsigned short* D  = (unsigned short*)d_ws;
    unsigned short* kb = (unsigned short*)((char*)d_ws + d_bytes);
    unsigned short* vb = (unsigned short*)((char*)d_ws + d_bytes + kb_bytes);

    // Phase 1: convert key & value to bf16
    const int n4 = nq * EMBED / 4;
    cvt_kernel<<<(n4 + 255) / 256, 256, 0, stream>>>(
        (const float4*)key, (const float4*)value, (ushort4*)kb, (ushort4*)vb, n4);

    // Phase 2: D = key . value^T  (64x64 tiles, 2-wave blocks)
    dim3 grid(nv / 64, nq / 64);
    gemm_nt_bf16<<<grid, 128, 0, stream>>>(kb, vb, D, nv);

    // Phase 3: bilinear gather + identity (2 queries per block)
    gather_kernel<<<nq / 2, 256, 0, stream>>>(D, identity, ref3d, spatial, out, nv);
}